// Round 3
// baseline (699.195 us; speedup 1.0000x reference)
//
#include <hip/hip_runtime.h>
#include <hip/hip_bf16.h>
#include <stdint.h>

// Problem constants (fixed by the reference setup)
#define NROWS 8192   // N (batch rows of x)
#define IN_F  4096   // K
#define OUT_F 4096   // N (output features)
#define RANK  16
#define SCALE 0.0025f  // SIGMA / sqrt(r) * SIGN = 0.01 / 4 * 1.0

typedef __bf16 bf16x8 __attribute__((ext_vector_type(8)));
typedef float f32x4 __attribute__((ext_vector_type(4)));
typedef float f32x16 __attribute__((ext_vector_type(16)));

// ---------------------------------------------------------------------------
// Kernel 1: Pbt[r][i] = sum_j P[i][j] * noise[j][r]   (Pb = P @ b_mat, stored
// transposed 16 x 4096). 4 P-rows per block (L2-stream blocking, R1: -~60us).
// ---------------------------------------------------------------------------
__global__ __launch_bounds__(256) void pb_kernel(const float* __restrict__ P,
                                                 const float* __restrict__ noise,
                                                 float* __restrict__ Pbt) {
  int i0 = blockIdx.x * 4;
  int tid = threadIdx.x;
  int lane = tid & 63;
  int wave = tid >> 6;
  float acc[4][RANK];
#pragma unroll
  for (int nn = 0; nn < 4; ++nn)
#pragma unroll
    for (int r = 0; r < RANK; ++r) acc[nn][r] = 0.f;
  const float* P0 = P + (size_t)i0 * IN_F;
  for (int j = tid; j < IN_F; j += 256) {
    const f32x4* brow = (const f32x4*)(noise + (size_t)j * RANK);
    f32x4 b0 = brow[0], b1 = brow[1], b2 = brow[2], b3 = brow[3];
#pragma unroll
    for (int nn = 0; nn < 4; ++nn) {
      float p = P0[(size_t)nn * IN_F + j];
#pragma unroll
      for (int q = 0; q < 4; ++q) {
        acc[nn][q] += p * b0[q];
        acc[nn][4 + q] += p * b1[q];
        acc[nn][8 + q] += p * b2[q];
        acc[nn][12 + q] += p * b3[q];
      }
    }
  }
#pragma unroll
  for (int off = 32; off > 0; off >>= 1)
#pragma unroll
    for (int nn = 0; nn < 4; ++nn)
#pragma unroll
      for (int r = 0; r < RANK; ++r) acc[nn][r] += __shfl_down(acc[nn][r], off, 64);
  __shared__ float red[4][4][RANK];
  if (lane == 0)
#pragma unroll
    for (int nn = 0; nn < 4; ++nn)
#pragma unroll
      for (int r = 0; r < RANK; ++r) red[wave][nn][r] = acc[nn][r];
  __syncthreads();
  if (tid < 4 * RANK) {
    int nn = tid >> 4, r = tid & 15;
    float s = red[0][nn][r] + red[1][nn][r] + red[2][nn][r] + red[3][nn][r];
    Pbt[(size_t)r * IN_F + i0 + nn] = s;
  }
}

// ---------------------------------------------------------------------------
// Kernel 2: Wb[n][k] = bf16( W[n][k] + SCALE * sum_r a_mat[n][r] * Pbt[r][k] )
// 4 W-rows per block (L2-stream blocking, verified R1).
// ---------------------------------------------------------------------------
__global__ __launch_bounds__(256) void wprep_kernel(const float* __restrict__ W,
                                                    const float* __restrict__ noise,
                                                    const float* __restrict__ Pbt,
                                                    __bf16* __restrict__ Wb) {
  int n0 = blockIdx.x * 4;
  int tid = threadIdx.x;
  __shared__ float arow[4][RANK];
  if (tid < 4 * RANK) {
    int nn = tid >> 4, r = tid & 15;
    arow[nn][r] = SCALE * noise[(size_t)(IN_F + n0 + nn) * RANK + r];
  }
  __syncthreads();
  int k0 = tid * 16;
  f32x4 o[4][4];
#pragma unroll
  for (int nn = 0; nn < 4; ++nn) {
    const f32x4* wr = (const f32x4*)(W + (size_t)(n0 + nn) * IN_F + k0);
#pragma unroll
    for (int q = 0; q < 4; ++q) o[nn][q] = wr[q];
  }
#pragma unroll
  for (int r = 0; r < RANK; ++r) {
    const f32x4* pr = (const f32x4*)(Pbt + (size_t)r * IN_F + k0);
    f32x4 p0 = pr[0], p1 = pr[1], p2 = pr[2], p3 = pr[3];
#pragma unroll
    for (int nn = 0; nn < 4; ++nn) {
      float ar = arow[nn][r];
#pragma unroll
      for (int q = 0; q < 4; ++q) {
        o[nn][0][q] += ar * p0[q];
        o[nn][1][q] += ar * p1[q];
        o[nn][2][q] += ar * p2[q];
        o[nn][3][q] += ar * p3[q];
      }
    }
  }
#pragma unroll
  for (int nn = 0; nn < 4; ++nn) {
    __align__(16) __bf16 ob[16];
#pragma unroll
    for (int q = 0; q < 4; ++q)
#pragma unroll
      for (int e = 0; e < 4; ++e) ob[q * 4 + e] = (__bf16)o[nn][q][e];
    *(uint4*)(Wb + (size_t)(n0 + nn) * IN_F + k0) = *(uint4*)&ob[0];
    *(uint4*)(Wb + (size_t)(n0 + nn) * IN_F + k0 + 8) = *(uint4*)&ob[8];
  }
}

// ---------------------------------------------------------------------------
// Kernel 3: cast x (f32) -> bf16   (unchanged; ~BW-bound)
// ---------------------------------------------------------------------------
__global__ __launch_bounds__(256) void xcast_kernel(const float* __restrict__ X,
                                                    __bf16* __restrict__ Xb) {
  size_t idx = ((size_t)blockIdx.x * 256 + threadIdx.x) * 8;
  f32x4 a = *(const f32x4*)(X + idx);
  f32x4 b = *(const f32x4*)(X + idx + 4);
  __align__(16) __bf16 ob[8];
#pragma unroll
  for (int q = 0; q < 4; q++) {
    ob[q] = (__bf16)a[q];
    ob[4 + q] = (__bf16)b[q];
  }
  *(uint4*)(Xb + idx) = *(uint4*)&ob[0];
}

// ---------------------------------------------------------------------------
// Kernel 4: main GEMM  C[m][n] = sum_k A[m][k]*B[n][k] + bias[n]
//
// Schedule (ledger-verified): 256x256 tile, BK=32, 512 thr = 8 waves
// (2M x 4N), per-wave 128x64 = 4x2 frags of v_mfma_f32_32x32x16_bf16.
// Quad-buffered LDS (4 x 32 KB), depth-3 prefetch, counted s_waitcnt
// vmcnt(10) in steady state (never 0), tail drains 8/4/0. Raw s_barrier.
//
// k-sliced LDS layout: A-tile stored as sA[g][row][8] bf16, g = 16B
// k-block (0..3). Fragment read for (row, g): byte = g*4096 + row*16,
// row linear in lane -> consecutive lanes read consecutive 16B ->
// conflict-free under ANY hw phasing model. Staging keeps LDS dest
// linear (base + tid*16, wave-uniform-base rule); global source is
// per-lane row-strided (16 B @ 8 KB stride); lines fully consumed
// across g-slices so HBM traffic unchanged.
// ---------------------------------------------------------------------------
__global__ __launch_bounds__(512, 2) void gemm_kernel(const __bf16* __restrict__ A,
                                                      const __bf16* __restrict__ B,
                                                      const float* __restrict__ bias,
                                                      float* __restrict__ C) {
  constexpr int K = IN_F;
  constexpr int N = OUT_F;
  constexpr int BK = 32;
  constexpr int NT = K / BK;      // 128
  constexpr int ABUF = 256 * BK;  // 8192 elements = 16 KB (one A or B tile)
  constexpr int BUFE = 2 * ABUF;  // one (A,B) buffer pair
  __shared__ __align__(16) __bf16 sh[4 * BUFE];  // 128 KiB

  const int tid = threadIdx.x;
  const int wave = tid >> 6;
  const int lane = tid & 63;
  const int l31 = lane & 31;
  const int lhi = lane >> 5;

  // XCD-aware swizzle: 64-wg contiguous chunk per XCD. 512 % 8 == 0 bijective.
  int bid = blockIdx.x;
  int wg = (bid & 7) * 64 + (bid >> 3);
  int by = wg >> 4;  // 0..31
  int bx = wg & 15;  // 0..15
  const int m0 = by * 256;
  const int n0 = bx * 256;

  const int wm = (wave >> 2) * 128;  // 0 or 128
  const int wn = (wave & 3) * 64;    // 0,64,128,192

  const __bf16* Ab = A + (size_t)m0 * K;
  const __bf16* Bb = B + (size_t)n0 * K;

  // Staging (k-sliced): per tile, A = 2 instrs (s=0,1), B = 2 instrs.
  // Instr s: thread tid covers g = 2s + (tid>>8), row = tid&255.
  // LDS dest byte = s*8192 + tid*16 (linear).  Global src = row's 16B at
  // k-block g.  Within a wave, g is uniform and rows are consecutive.
  const int srow = tid & 255;
  const int sg = (tid >> 8) & 1;  // +2s added per instr

  f32x16 acc[4][2];
#pragma unroll
  for (int i = 0; i < 4; ++i)
#pragma unroll
    for (int j = 0; j < 2; ++j) acc[i][j] = (f32x16)(0.f);

  // Fragment-read byte offsets within a tile buffer: g = ks*2 + kh (kh = lhi)
  // byte = (ks*2 + kh)*4096 + row*16;  kh/row folded into per-lane base.
  int aoff[4], boff[2];
#pragma unroll
  for (int mf = 0; mf < 4; ++mf) aoff[mf] = lhi * 4096 + (wm + mf * 32 + l31) * 16;
#pragma unroll
  for (int nf = 0; nf < 2; ++nf) boff[nf] = lhi * 4096 + (wn + nf * 32 + l31) * 16;

  auto stageA = [&](int tt, int bb) {
#pragma unroll
    for (int s = 0; s < 2; ++s) {
      const __bf16* g = Ab + (size_t)srow * K + tt * BK + (2 * s + sg) * 8;
      __builtin_amdgcn_global_load_lds(
          (__attribute__((address_space(1))) void*)g,
          (__attribute__((address_space(3))) void*)((char*)(sh + bb * BUFE) + s * 8192 + tid * 16),
          16, 0, 0);
    }
  };
  auto stageB = [&](int tt, int bb) {
#pragma unroll
    for (int s = 0; s < 2; ++s) {
      const __bf16* g = Bb + (size_t)srow * K + tt * BK + (2 * s + sg) * 8;
      __builtin_amdgcn_global_load_lds(
          (__attribute__((address_space(1))) void*)g,
          (__attribute__((address_space(3))) void*)((char*)(sh + bb * BUFE + ABUF) + s * 8192 + tid * 16),
          16, 0, 0);
    }
  };

  auto do_ks = [&](const __bf16* sa, const __bf16* sbv, int ks) {
    bf16x8 af[4], bfr[2];
#pragma unroll
    for (int mf = 0; mf < 4; ++mf)
      af[mf] = *(const bf16x8*)((const char*)sa + ks * 8192 + aoff[mf]);
#pragma unroll
    for (int nf = 0; nf < 2; ++nf)
      bfr[nf] = *(const bf16x8*)((const char*)sbv + ks * 8192 + boff[nf]);
    __builtin_amdgcn_s_setprio(1);
#pragma unroll
    for (int mf = 0; mf < 4; ++mf)
#pragma unroll
      for (int nf = 0; nf < 2; ++nf)
        acc[mf][nf] = __builtin_amdgcn_mfma_f32_32x32x16_bf16(af[mf], bfr[nf], acc[mf][nf], 0, 0, 0);
    __builtin_amdgcn_s_setprio(0);
  };

  // prologue: tiles 0,1,2 (issue order per wave = [A2,B2] per tile)
  stageA(0, 0); stageB(0, 0);
  stageA(1, 1); stageB(1, 1);
  stageA(2, 2); stageB(2, 2);

#pragma unroll 2
  for (int t = 0; t < NT - 3; ++t) {
    const int bb = t & 3;
    const int nb = (t + 3) & 3;
    __builtin_amdgcn_s_barrier();  // A: all waves done reading tile t-1's buffer
    stageA(t + 3, nb);
    asm volatile("s_waitcnt vmcnt(10)" ::: "memory");  // newest 10 = A(t+3),B(t+2),A(t+2),B(t+1),A(t+1) -> tile t landed
    __builtin_amdgcn_s_barrier();  // B: tile t landed for ALL waves
    const __bf16* sa = sh + bb * BUFE;
    const __bf16* sbv = sa + ABUF;
    do_ks(sa, sbv, 0);
    stageB(t + 3, nb);  // buf[nb] != buf[bb]; all waves past barrier B
    do_ks(sa, sbv, 1);
  }
  // tail: tiles NT-3, NT-2, NT-1 (no staging; drain 8 -> 4 -> 0)
  {
    const __bf16* sa = sh + ((NT - 3) & 3) * BUFE;
    asm volatile("s_waitcnt vmcnt(8)" ::: "memory");
    __builtin_amdgcn_s_barrier();
    do_ks(sa, sa + ABUF, 0);
    do_ks(sa, sa + ABUF, 1);
  }
  {
    const __bf16* sa = sh + ((NT - 2) & 3) * BUFE;
    asm volatile("s_waitcnt vmcnt(4)" ::: "memory");
    __builtin_amdgcn_s_barrier();
    do_ks(sa, sa + ABUF, 0);
    do_ks(sa, sa + ABUF, 1);
  }
  {
    const __bf16* sa = sh + ((NT - 1) & 3) * BUFE;
    asm volatile("s_waitcnt vmcnt(0)" ::: "memory");
    __builtin_amdgcn_s_barrier();
    do_ks(sa, sa + ABUF, 0);
    do_ks(sa, sa + ABUF, 1);
  }

  // Epilogue: 32x32 C/D layout col = lane&31,
  // row = (reg&3) + 8*(reg>>2) + 4*(lane>>5)   [m74/m101]
  const int cn = l31;
  const int rb = 4 * lhi;
#pragma unroll
  for (int nf = 0; nf < 2; ++nf) {
    int col = n0 + wn + nf * 32 + cn;
    float bv = bias[col];
#pragma unroll
    for (int mf = 0; mf < 4; ++mf) {
      int rowb = m0 + wm + mf * 32 + rb;
#pragma unroll
      for (int reg = 0; reg < 16; ++reg) {
        int row = rowb + (reg & 3) + 8 * (reg >> 2);
        C[(size_t)row * N + col] = acc[mf][nf][reg] + bv;
      }
    }
  }
}

// ---------------------------------------------------------------------------
extern "C" void kernel_launch(void* const* d_in, const int* in_sizes, int n_in,
                              void* d_out, int out_size, void* d_ws, size_t ws_size,
                              hipStream_t stream) {
  const float* x = (const float*)d_in[0];       // 8192 x 4096
  const float* weight = (const float*)d_in[1];  // 4096 x 4096
  const float* bias = (const float*)d_in[2];    // 4096
  const float* noise = (const float*)d_in[3];   // 8192 x 16
  const float* P = (const float*)d_in[4];       // 4096 x 4096
  float* out = (float*)d_out;                   // 8192 x 4096

  char* ws = (char*)d_ws;
  __bf16* Xb = (__bf16*)ws;                                   // 64 MB
  __bf16* Wb = (__bf16*)(ws + (size_t)NROWS * IN_F * 2);      // 32 MB
  float* Pbt = (float*)(ws + (size_t)NROWS * IN_F * 2 + (size_t)OUT_F * IN_F * 2);  // 256 KB

  pb_kernel<<<IN_F / 4, 256, 0, stream>>>(P, noise, Pbt);
  wprep_kernel<<<OUT_F / 4, 256, 0, stream>>>(weight, noise, Pbt, Wb);
  xcast_kernel<<<(int)(((size_t)NROWS * IN_F) / (8 * 256)), 256, 0, stream>>>(x, Xb);
  gemm_kernel<<<dim3(512), 512, 0, stream>>>(Xb, Wb, bias, out);
}

// Round 4
// 586.245 us; speedup vs baseline: 1.1927x; 1.1927x over previous
//
#include <hip/hip_runtime.h>
#include <hip/hip_bf16.h>
#include <stdint.h>

// Problem constants (fixed by the reference setup)
#define NROWS 8192   // N (batch rows of x)
#define IN_F  4096   // K
#define OUT_F 4096   // N (output features)
#define RANK  16
#define SCALE 0.0025f  // SIGMA / sqrt(r) * SIGN = 0.01 / 4 * 1.0

typedef __bf16 bf16x8 __attribute__((ext_vector_type(8)));
typedef float f32x4 __attribute__((ext_vector_type(4)));
typedef float f32x16 __attribute__((ext_vector_type(16)));

// ---------------------------------------------------------------------------
// Kernel 1: Pbt[r][i] = sum_j P[i][j] * noise[j][r]   (Pb = P @ b_mat, stored
// transposed 16 x 4096). R4 restructure: 4 lanes share one j-row, each lane
// reads ONE f32x4 of noise -> 64 lanes x 16 B fully contiguous (was stride-64B
// per lane = 64 cache lines/instr). P reads are 4-lane broadcast.
// Wave w owns j in [w*1024, (w+1)*1024); 64 iters of 16 rows.
// ---------------------------------------------------------------------------
__global__ __launch_bounds__(256) void pb_kernel(const float* __restrict__ P,
                                                 const float* __restrict__ noise,
                                                 float* __restrict__ Pbt) {
  int i0 = blockIdx.x * 4;
  int tid = threadIdx.x;
  int lane = tid & 63;
  int wave = tid >> 6;
  int rq = lane & 3;   // which f32x4 of the 16 r's
  int jo = lane >> 2;  // 0..15: row within the 16-row iter chunk

  f32x4 acc[4];
#pragma unroll
  for (int nn = 0; nn < 4; ++nn) acc[nn] = (f32x4)(0.f);

  const float* P0 = P + (size_t)i0 * IN_F;
  int jbase = wave * 1024;
  for (int it = 0; it < 64; ++it) {
    int jj = jbase + it * 16 + jo;
    f32x4 nv = *(const f32x4*)(noise + (size_t)jj * RANK + rq * 4);
#pragma unroll
    for (int nn = 0; nn < 4; ++nn) {
      float p = P0[(size_t)nn * IN_F + jj];
      acc[nn] += p * nv;
    }
  }
  // reduce over the 16 jo-groups (stride-4 lanes share rq)
#pragma unroll
  for (int off = 4; off <= 32; off <<= 1)
#pragma unroll
    for (int nn = 0; nn < 4; ++nn)
#pragma unroll
      for (int q = 0; q < 4; ++q) acc[nn][q] += __shfl_down(acc[nn][q], off, 64);

  __shared__ f32x4 red[4][4][4];  // [wave][rq][nn]
  if (lane < 4)
#pragma unroll
    for (int nn = 0; nn < 4; ++nn) red[wave][lane][nn] = acc[nn];
  __syncthreads();
  if (tid < 64) {
    int nn = tid >> 4, r = tid & 15;
    float s = red[0][r >> 2][nn][r & 3] + red[1][r >> 2][nn][r & 3] +
              red[2][r >> 2][nn][r & 3] + red[3][r >> 2][nn][r & 3];
    Pbt[(size_t)r * IN_F + i0 + nn] = s;
  }
}

// ---------------------------------------------------------------------------
// Kernel 2 (fused): blocks [0,1024) = wprep, blocks [1024,5120) = xcast.
// Independent work items -> overlapping execution, one launch boundary saved.
//
// wprep: Wb[n][k] = bf16( W[n][k] + SCALE * sum_r a[n][r] * Pbt[r][k] ).
// R4 restructure: 4 col-chunks of 1024 floats; within a chunk thread t owns
// f32x4 at col t*4 -> all W/Pbt loads and Wb stores lane-contiguous (was
// lane-stride 64 B).
//
// xcast: x f32 -> bf16, grid-stride x4 (4096 blocks instead of 16384).
// ---------------------------------------------------------------------------
__global__ __launch_bounds__(256) void prep_kernel(const float* __restrict__ W,
                                                   const float* __restrict__ noise,
                                                   const float* __restrict__ Pbt,
                                                   __bf16* __restrict__ Wb,
                                                   const float* __restrict__ X,
                                                   __bf16* __restrict__ Xb) {
  int tid = threadIdx.x;
  __shared__ float arow[4][RANK];
  if (blockIdx.x < 1024) {
    // ---- wprep ----
    int n0 = blockIdx.x * 4;
    if (tid < 64) {
      int nn = tid >> 4, r = tid & 15;
      arow[nn][r] = SCALE * noise[(size_t)(IN_F + n0 + nn) * RANK + r];
    }
    __syncthreads();
#pragma unroll
    for (int c = 0; c < 4; ++c) {
      int f = c * 1024 + tid * 4;
      f32x4 o[4];
#pragma unroll
      for (int nn = 0; nn < 4; ++nn)
        o[nn] = *(const f32x4*)(W + (size_t)(n0 + nn) * IN_F + f);
#pragma unroll
      for (int r = 0; r < RANK; ++r) {
        f32x4 pv = *(const f32x4*)(Pbt + (size_t)r * IN_F + f);
#pragma unroll
        for (int nn = 0; nn < 4; ++nn) o[nn] += arow[nn][r] * pv;
      }
#pragma unroll
      for (int nn = 0; nn < 4; ++nn) {
        __align__(8) __bf16 ob[4];
#pragma unroll
        for (int q = 0; q < 4; ++q) ob[q] = (__bf16)o[nn][q];
        *(uint2*)(Wb + (size_t)(n0 + nn) * IN_F + f) = *(uint2*)&ob[0];
      }
    }
  } else {
    // ---- xcast (grid-stride x4) ----
    size_t idx = ((size_t)(blockIdx.x - 1024) * 256 + tid) * 8;
    const size_t stride = (size_t)4096 * 256 * 8;
#pragma unroll
    for (int it = 0; it < 4; ++it, idx += stride) {
      f32x4 a = *(const f32x4*)(X + idx);
      f32x4 b = *(const f32x4*)(X + idx + 4);
      __align__(16) __bf16 ob[8];
#pragma unroll
      for (int q = 0; q < 4; ++q) {
        ob[q] = (__bf16)a[q];
        ob[4 + q] = (__bf16)b[q];
      }
      *(uint4*)(Xb + idx) = *(uint4*)&ob[0];
    }
  }
}

// ---------------------------------------------------------------------------
// Kernel 4: main GEMM — EXACT revert to the verified R1 version (260 µs,
// MfmaUtil 50%, conflicts 2.5e7). 256x256 tile, BK=32, 8 waves (2M x 4N),
// 4x2 frags of v_mfma_f32_32x32x16_bf16, quad-buffered LDS, depth-3
// prefetch, counted vmcnt(10) steady-state, tail 8/4/0, raw s_barrier.
// Known residual: 4-way read conflict (lanes {q,q+8,q+16,q+24} share
// slot+parity with 32-row fragments) — next-round target via 16x16 frags.
// ---------------------------------------------------------------------------
__global__ __launch_bounds__(512, 2) void gemm_kernel(const __bf16* __restrict__ A,
                                                      const __bf16* __restrict__ B,
                                                      const float* __restrict__ bias,
                                                      float* __restrict__ C) {
  constexpr int K = IN_F;
  constexpr int N = OUT_F;
  constexpr int BK = 32;
  constexpr int NT = K / BK;      // 128
  constexpr int ABUF = 256 * BK;  // 8192 elements = 16 KB (one A or B tile)
  constexpr int BUFE = 2 * ABUF;  // one (A,B) buffer pair
  __shared__ __align__(16) __bf16 sh[4 * BUFE];  // 128 KiB

  const int tid = threadIdx.x;
  const int wave = tid >> 6;
  const int lane = tid & 63;
  const int l31 = lane & 31;
  const int lhi = lane >> 5;
  const int q2 = l31 >> 1;

  // XCD-aware swizzle: 64-wg contiguous chunk per XCD. 512 % 8 == 0 bijective.
  int bid = blockIdx.x;
  int wg = (bid & 7) * 64 + (bid >> 3);
  int by = wg >> 4;  // 0..31
  int bx = wg & 15;  // 0..15
  const int m0 = by * 256;
  const int n0 = bx * 256;

  const int wm = (wave >> 2) * 128;  // 0 or 128
  const int wn = (wave & 3) * 64;    // 0,64,128,192

  const __bf16* Ab = A + (size_t)m0 * K;
  const __bf16* Bb = B + (size_t)n0 * K;

  // Staging: one wave-issue = 64 lanes x 16 B = 1 KB = 16 rows of 64 B.
  // Thread covers row (s*128 + tid>>2), LDS slot p = tid&3; it fetches
  // global 16B-block (p - (row>>1))&3; (row>>1)&3 == (tid>>3)&3.
  const int srow = tid >> 2;
  const int sblk = ((tid & 3) - ((tid >> 3) & 3)) & 3;
  const int scol = sblk * 8;       // element col within BK
  const int ldsw = wave * 512;     // elements: wave chunk within an 8 KB half

  f32x16 acc[4][2];
#pragma unroll
  for (int i = 0; i < 4; ++i)
#pragma unroll
    for (int j = 0; j < 2; ++j) acc[i][j] = (f32x16)(0.f);

  // fragment-read address precompute (all static indexing downstream)
  int rowA[4], rowB[2];
#pragma unroll
  for (int mf = 0; mf < 4; ++mf) rowA[mf] = (wm + mf * 32 + l31) * BK;
#pragma unroll
  for (int nf = 0; nf < 2; ++nf) rowB[nf] = (wn + nf * 32 + l31) * BK;
  // block c = ks*2 + lhi ; slot p = (c + (r>>1))&3, (r>>1)&3 == (l31>>1)&3
  const int po0 = ((lhi + q2) & 3) * 8;      // ks = 0
  const int po1 = ((2 + lhi + q2) & 3) * 8;  // ks = 1

  auto stageA = [&](int tt, int bb) {
#pragma unroll
    for (int s = 0; s < 2; ++s) {
      const __bf16* g = Ab + (size_t)(s * 128 + srow) * K + tt * BK + scol;
      __builtin_amdgcn_global_load_lds(
          (__attribute__((address_space(1))) void*)g,
          (__attribute__((address_space(3))) void*)(sh + bb * BUFE + s * 4096 + ldsw),
          16, 0, 0);
    }
  };
  auto stageB = [&](int tt, int bb) {
#pragma unroll
    for (int s = 0; s < 2; ++s) {
      const __bf16* g = Bb + (size_t)(s * 128 + srow) * K + tt * BK + scol;
      __builtin_amdgcn_global_load_lds(
          (__attribute__((address_space(1))) void*)g,
          (__attribute__((address_space(3))) void*)(sh + bb * BUFE + ABUF + s * 4096 + ldsw),
          16, 0, 0);
    }
  };

  auto do_ks = [&](const __bf16* sa, const __bf16* sbv, int po) {
    bf16x8 af[4], bfr[2];
#pragma unroll
    for (int mf = 0; mf < 4; ++mf) af[mf] = *(const bf16x8*)(sa + rowA[mf] + po);
#pragma unroll
    for (int nf = 0; nf < 2; ++nf) bfr[nf] = *(const bf16x8*)(sbv + rowB[nf] + po);
    __builtin_amdgcn_s_setprio(1);
#pragma unroll
    for (int mf = 0; mf < 4; ++mf)
#pragma unroll
      for (int nf = 0; nf < 2; ++nf)
        acc[mf][nf] = __builtin_amdgcn_mfma_f32_32x32x16_bf16(af[mf], bfr[nf], acc[mf][nf], 0, 0, 0);
    __builtin_amdgcn_s_setprio(0);
  };

  // prologue: tiles 0,1,2 (issue order per wave = [A2,B2] per tile)
  stageA(0, 0); stageB(0, 0);
  stageA(1, 1); stageB(1, 1);
  stageA(2, 2); stageB(2, 2);

#pragma unroll 2
  for (int t = 0; t < NT - 3; ++t) {
    const int bb = t & 3;
    const int nb = (t + 3) & 3;
    __builtin_amdgcn_s_barrier();  // A: all waves done reading tile t-1's buffer
    stageA(t + 3, nb);
    asm volatile("s_waitcnt vmcnt(10)" ::: "memory");  // newest 10 = A(t+3),B(t+2),A(t+2),B(t+1),A(t+1) -> tile t landed
    __builtin_amdgcn_s_barrier();  // B: tile t landed for ALL waves
    const __bf16* sa = sh + bb * BUFE;
    const __bf16* sbv = sa + ABUF;
    do_ks(sa, sbv, po0);
    stageB(t + 3, nb);  // buf[nb] != buf[bb]; all waves past barrier B
    do_ks(sa, sbv, po1);
  }
  // tail: tiles NT-3, NT-2, NT-1 (no staging; drain 8 -> 4 -> 0)
  {
    const __bf16* sa = sh + ((NT - 3) & 3) * BUFE;
    asm volatile("s_waitcnt vmcnt(8)" ::: "memory");
    __builtin_amdgcn_s_barrier();
    do_ks(sa, sa + ABUF, po0);
    do_ks(sa, sa + ABUF, po1);
  }
  {
    const __bf16* sa = sh + ((NT - 2) & 3) * BUFE;
    asm volatile("s_waitcnt vmcnt(4)" ::: "memory");
    __builtin_amdgcn_s_barrier();
    do_ks(sa, sa + ABUF, po0);
    do_ks(sa, sa + ABUF, po1);
  }
  {
    const __bf16* sa = sh + ((NT - 1) & 3) * BUFE;
    asm volatile("s_waitcnt vmcnt(0)" ::: "memory");
    __builtin_amdgcn_s_barrier();
    do_ks(sa, sa + ABUF, po0);
    do_ks(sa, sa + ABUF, po1);
  }

  // Epilogue: 32x32 C/D layout col = lane&31,
  // row = (reg&3) + 8*(reg>>2) + 4*(lane>>5)   [m74/m101]
  const int cn = l31;
  const int rb = 4 * lhi;
#pragma unroll
  for (int nf = 0; nf < 2; ++nf) {
    int col = n0 + wn + nf * 32 + cn;
    float bv = bias[col];
#pragma unroll
    for (int mf = 0; mf < 4; ++mf) {
      int rowb = m0 + wm + mf * 32 + rb;
#pragma unroll
      for (int reg = 0; reg < 16; ++reg) {
        int row = rowb + (reg & 3) + 8 * (reg >> 2);
        C[(size_t)row * N + col] = acc[mf][nf][reg] + bv;
      }
    }
  }
}

// ---------------------------------------------------------------------------
extern "C" void kernel_launch(void* const* d_in, const int* in_sizes, int n_in,
                              void* d_out, int out_size, void* d_ws, size_t ws_size,
                              hipStream_t stream) {
  const float* x = (const float*)d_in[0];       // 8192 x 4096
  const float* weight = (const float*)d_in[1];  // 4096 x 4096
  const float* bias = (const float*)d_in[2];    // 4096
  const float* noise = (const float*)d_in[3];   // 8192 x 16
  const float* P = (const float*)d_in[4];       // 4096 x 4096
  float* out = (float*)d_out;                   // 8192 x 4096

  char* ws = (char*)d_ws;
  __bf16* Xb = (__bf16*)ws;                                   // 64 MB
  __bf16* Wb = (__bf16*)(ws + (size_t)NROWS * IN_F * 2);      // 32 MB
  float* Pbt = (float*)(ws + (size_t)NROWS * IN_F * 2 + (size_t)OUT_F * IN_F * 2);  // 256 KB

  pb_kernel<<<IN_F / 4, 256, 0, stream>>>(P, noise, Pbt);
  prep_kernel<<<1024 + 4096, 256, 0, stream>>>(weight, noise, Pbt, Wb, x, Xb);
  gemm_kernel<<<dim3(512), 512, 0, stream>>>(Xb, Wb, bias, out);
}

// Round 6
// 582.252 us; speedup vs baseline: 1.2008x; 1.0069x over previous
//
#include <hip/hip_runtime.h>
#include <hip/hip_bf16.h>
#include <stdint.h>

// Problem constants (fixed by the reference setup)
#define NROWS 8192   // N (batch rows of x)
#define IN_F  4096   // K
#define OUT_F 4096   // N (output features)
#define RANK  16
#define SCALE 0.0025f  // SIGMA / sqrt(r) * SIGN = 0.01 / 4 * 1.0

typedef __bf16 bf16x8 __attribute__((ext_vector_type(8)));
typedef float f32x4 __attribute__((ext_vector_type(4)));
typedef float f32x16 __attribute__((ext_vector_type(16)));

// ---------------------------------------------------------------------------
// Kernel 1: Pbt[r][i] = sum_j P[i][j] * noise[j][r]  (frozen from R4)
// ---------------------------------------------------------------------------
__global__ __launch_bounds__(256) void pb_kernel(const float* __restrict__ P,
                                                 const float* __restrict__ noise,
                                                 float* __restrict__ Pbt) {
  int i0 = blockIdx.x * 4;
  int tid = threadIdx.x;
  int lane = tid & 63;
  int wave = tid >> 6;
  int rq = lane & 3;   // which f32x4 of the 16 r's
  int jo = lane >> 2;  // 0..15: row within the 16-row iter chunk

  f32x4 acc[4];
#pragma unroll
  for (int nn = 0; nn < 4; ++nn) acc[nn] = (f32x4)(0.f);

  const float* P0 = P + (size_t)i0 * IN_F;
  int jbase = wave * 1024;
  for (int it = 0; it < 64; ++it) {
    int jj = jbase + it * 16 + jo;
    f32x4 nv = *(const f32x4*)(noise + (size_t)jj * RANK + rq * 4);
#pragma unroll
    for (int nn = 0; nn < 4; ++nn) {
      float p = P0[(size_t)nn * IN_F + jj];
      acc[nn] += p * nv;
    }
  }
#pragma unroll
  for (int off = 4; off <= 32; off <<= 1)
#pragma unroll
    for (int nn = 0; nn < 4; ++nn)
#pragma unroll
      for (int q = 0; q < 4; ++q) acc[nn][q] += __shfl_down(acc[nn][q], off, 64);

  __shared__ f32x4 red[4][4][4];  // [wave][rq][nn]
  if (lane < 4)
#pragma unroll
    for (int nn = 0; nn < 4; ++nn) red[wave][lane][nn] = acc[nn];
  __syncthreads();
  if (tid < 64) {
    int nn = tid >> 4, r = tid & 15;
    float s = red[0][r >> 2][nn][r & 3] + red[1][r >> 2][nn][r & 3] +
              red[2][r >> 2][nn][r & 3] + red[3][r >> 2][nn][r & 3];
    Pbt[(size_t)r * IN_F + i0 + nn] = s;
  }
}

// ---------------------------------------------------------------------------
// Kernel 2 (fused wprep + xcast, frozen from R4)
// ---------------------------------------------------------------------------
__global__ __launch_bounds__(256) void prep_kernel(const float* __restrict__ W,
                                                   const float* __restrict__ noise,
                                                   const float* __restrict__ Pbt,
                                                   __bf16* __restrict__ Wb,
                                                   const float* __restrict__ X,
                                                   __bf16* __restrict__ Xb) {
  int tid = threadIdx.x;
  __shared__ float arow[4][RANK];
  if (blockIdx.x < 1024) {
    // ---- wprep ----
    int n0 = blockIdx.x * 4;
    if (tid < 64) {
      int nn = tid >> 4, r = tid & 15;
      arow[nn][r] = SCALE * noise[(size_t)(IN_F + n0 + nn) * RANK + r];
    }
    __syncthreads();
#pragma unroll
    for (int c = 0; c < 4; ++c) {
      int f = c * 1024 + tid * 4;
      f32x4 o[4];
#pragma unroll
      for (int nn = 0; nn < 4; ++nn)
        o[nn] = *(const f32x4*)(W + (size_t)(n0 + nn) * IN_F + f);
#pragma unroll
      for (int r = 0; r < RANK; ++r) {
        f32x4 pv = *(const f32x4*)(Pbt + (size_t)r * IN_F + f);
#pragma unroll
        for (int nn = 0; nn < 4; ++nn) o[nn] += arow[nn][r] * pv;
      }
#pragma unroll
      for (int nn = 0; nn < 4; ++nn) {
        __align__(8) __bf16 ob[4];
#pragma unroll
        for (int q = 0; q < 4; ++q) ob[q] = (__bf16)o[nn][q];
        *(uint2*)(Wb + (size_t)(n0 + nn) * IN_F + f) = *(uint2*)&ob[0];
      }
    }
  } else {
    // ---- xcast (grid-stride x4) ----
    size_t idx = ((size_t)(blockIdx.x - 1024) * 256 + tid) * 8;
    const size_t stride = (size_t)4096 * 256 * 8;
#pragma unroll
    for (int it = 0; it < 4; ++it, idx += stride) {
      f32x4 a = *(const f32x4*)(X + idx);
      f32x4 b = *(const f32x4*)(X + idx + 4);
      __align__(16) __bf16 ob[8];
#pragma unroll
      for (int q = 0; q < 4; ++q) {
        ob[q] = (__bf16)a[q];
        ob[4 + q] = (__bf16)b[q];
      }
      *(uint4*)(Xb + idx) = *(uint4*)&ob[0];
    }
  }
}

// ---------------------------------------------------------------------------
// Kernel 4: main GEMM  C[m][n] = sum_k A[m][k]*B[n][k] + bias[n]
//
// R5/R6: BK 32 -> 64. Rationale (bank arithmetic, closed-form): with 64 B
// LDS rows (BK=32) a column-read's same-parity lanes must share 4 slots
// -> >=2-way conflict for ANY rotation (measured +4cy/b128). 128 B rows
// (BK=64) give 8 slots; rotation slot = (kb + row)&7 puts lane bank =
// slot*4 (row stride = 32 banks exactly), so 8 consecutive lanes tile
// all 32 banks -> conflict-free BY ARITHMETIC, no phasing assumption.
// [m201 regime: st_16x32, conflicts 37.8M->267K, +29-35%]
//
// Double-buffered (2 x 64 KB = 128 KB), 2 barriers per BK=64 tile (half
// the barrier rate of R1). Split staging: stageA(t+1) at loop top (full-
// tile prefetch lead), stageB(t+1) after ks1 (half-tile lead). Counted
// vmcnt ledger (per-wave, 4 VMEM instr per stage call):
//   top of iter t: outstanding <= {B(t),A(t)} = 8
//   after stageA(t+1): {A(t+1),B(t),A(t)} = 12
//   s_waitcnt vmcnt(4): drains A(t),B(t) -> tile t resident; barrierB ->
//   resident for ALL waves. stageB(t+1) after barrierB + own compute ->
//   buf[(t+1)&1] (= tile t-1's buffer) safe: barrierA at top of iter t
//   followed all waves' compute of t-1. Tail: vmcnt(0), no staging.
// ---------------------------------------------------------------------------
__global__ __launch_bounds__(512, 2) void gemm_kernel(const __bf16* __restrict__ A,
                                                      const __bf16* __restrict__ B,
                                                      const float* __restrict__ bias,
                                                      float* __restrict__ C) {
  constexpr int K = IN_F;
  constexpr int N = OUT_F;
  constexpr int BK = 64;
  constexpr int NT = K / BK;       // 64
  constexpr int ABUF = 256 * BK;   // 16384 elements = 32 KB (one A or B tile)
  constexpr int BUFE = 2 * ABUF;   // one (A,B) buffer pair = 64 KB
  __shared__ __align__(16) __bf16 sh[2 * BUFE];  // 128 KiB

  const int tid = threadIdx.x;
  const int wave = tid >> 6;
  const int lane = tid & 63;
  const int l31 = lane & 31;
  const int lhi = lane >> 5;

  // XCD-aware swizzle: 64-wg contiguous chunk per XCD. 512 % 8 == 0 bijective.
  int bid = blockIdx.x;
  int wg = (bid & 7) * 64 + (bid >> 3);
  int by = wg >> 4;  // 0..31
  int bx = wg & 15;  // 0..15
  const int m0 = by * 256;
  const int n0 = bx * 256;

  const int wm = (wave >> 2) * 128;  // 0 or 128
  const int wn = (wave & 3) * 64;    // 0,64,128,192

  const __bf16* Ab = A + (size_t)m0 * K;
  const __bf16* Bb = B + (size_t)n0 * K;

  // Staging: per call, 512 threads x 16 B = 8 KB = 64 rows of 128 B.
  // Thread -> row (s*64 + tid>>3), LDS slot p = tid&7 (dest linear:
  // byte = s*8192 + tid*16). Storage rule: slot p of row r holds global
  // 16B-block b with p = (b + r)&7  =>  fetch b = (p - r)&7.
  const int srow = tid >> 3;                       // row within 64-row chunk
  const int sblk = ((tid & 7) - ((tid >> 3) & 7)) & 7;  // global 16B-block
  const int scol = sblk * 8;                       // element col within BK

  f32x16 acc[4][2];
#pragma unroll
  for (int i = 0; i < 4; ++i)
#pragma unroll
    for (int j = 0; j < 2; ++j) acc[i][j] = (f32x16)(0.f);

  // Fragment reads: global k-block kb = ks*2 + lhi of row r lives at slot
  // (kb + r)&7; r&7 == l31&7, so rotation byte-offset is frag-independent:
  int rot16[4];
#pragma unroll
  for (int ks = 0; ks < 4; ++ks) rot16[ks] = ((2 * ks + lhi + l31) & 7) * 16;
  // Row byte bases (rows are 128 B):
  int rbA[4], rbB[2];
#pragma unroll
  for (int mf = 0; mf < 4; ++mf) rbA[mf] = (wm + mf * 32 + l31) * 128;
#pragma unroll
  for (int nf = 0; nf < 2; ++nf) rbB[nf] = (wn + nf * 32 + l31) * 128;

  auto stageA = [&](int tt, int bb) {
#pragma unroll
    for (int s = 0; s < 4; ++s) {
      const __bf16* g = Ab + (size_t)(s * 64 + srow) * K + tt * BK + scol;
      __builtin_amdgcn_global_load_lds(
          (__attribute__((address_space(1))) void*)g,
          (__attribute__((address_space(3))) void*)((char*)(sh + bb * BUFE) + s * 8192 + tid * 16),
          16, 0, 0);
    }
  };
  auto stageB = [&](int tt, int bb) {
#pragma unroll
    for (int s = 0; s < 4; ++s) {
      const __bf16* g = Bb + (size_t)(s * 64 + srow) * K + tt * BK + scol;
      __builtin_amdgcn_global_load_lds(
          (__attribute__((address_space(1))) void*)g,
          (__attribute__((address_space(3))) void*)((char*)(sh + bb * BUFE + ABUF) + s * 8192 + tid * 16),
          16, 0, 0);
    }
  };

  auto do_ks = [&](const __bf16* sa, const __bf16* sbv, int ks) {
    bf16x8 af[4], bfr[2];
#pragma unroll
    for (int mf = 0; mf < 4; ++mf)
      af[mf] = *(const bf16x8*)((const char*)sa + rbA[mf] + rot16[ks]);
#pragma unroll
    for (int nf = 0; nf < 2; ++nf)
      bfr[nf] = *(const bf16x8*)((const char*)sbv + rbB[nf] + rot16[ks]);
    __builtin_amdgcn_s_setprio(1);
#pragma unroll
    for (int mf = 0; mf < 4; ++mf)
#pragma unroll
      for (int nf = 0; nf < 2; ++nf)
        acc[mf][nf] = __builtin_amdgcn_mfma_f32_32x32x16_bf16(af[mf], bfr[nf], acc[mf][nf], 0, 0, 0);
    __builtin_amdgcn_s_setprio(0);
  };

  // prologue: tile 0 fully staged (A then B -> per-wave order {A(0),B(0)})
  stageA(0, 0);
  stageB(0, 0);

  for (int t = 0; t < NT - 1; ++t) {
    const int bb = t & 1;
    const int nb = bb ^ 1;
    __builtin_amdgcn_s_barrier();  // A: all waves finished computing tile t-1
    stageA(t + 1, nb);             // safe: buf[nb] last read for tile t-1
    asm volatile("s_waitcnt vmcnt(4)" ::: "memory");  // drains A(t),B(t); keeps A(t+1)
    __builtin_amdgcn_s_barrier();  // B: tile t resident for ALL waves
    const __bf16* sa = sh + bb * BUFE;
    const __bf16* sbv = sa + ABUF;
    do_ks(sa, sbv, 0);
    do_ks(sa, sbv, 1);
    stageB(t + 1, nb);             // past barrier B -> no wave still reads buf[nb]
    do_ks(sa, sbv, 2);
    do_ks(sa, sbv, 3);
  }
  // tail: tile NT-1 (no staging)
  {
    const __bf16* sa = sh + ((NT - 1) & 1) * BUFE;
    __builtin_amdgcn_s_barrier();
    asm volatile("s_waitcnt vmcnt(0)" ::: "memory");
    __builtin_amdgcn_s_barrier();
    do_ks(sa, sa + ABUF, 0);
    do_ks(sa, sa + ABUF, 1);
    do_ks(sa, sa + ABUF, 2);
    do_ks(sa, sa + ABUF, 3);
  }

  // Epilogue: 32x32 C/D layout col = lane&31,
  // row = (reg&3) + 8*(reg>>2) + 4*(lane>>5)   [m74/m101]
  const int cn = l31;
  const int rb = 4 * lhi;
#pragma unroll
  for (int nf = 0; nf < 2; ++nf) {
    int col = n0 + wn + nf * 32 + cn;
    float bv = bias[col];
#pragma unroll
    for (int mf = 0; mf < 4; ++mf) {
      int rowb = m0 + wm + mf * 32 + rb;
#pragma unroll
      for (int reg = 0; reg < 16; ++reg) {
        int row = rowb + (reg & 3) + 8 * (reg >> 2);
        C[(size_t)row * N + col] = acc[mf][nf][reg] + bv;
      }
    }
  }
}

// ---------------------------------------------------------------------------
extern "C" void kernel_launch(void* const* d_in, const int* in_sizes, int n_in,
                              void* d_out, int out_size, void* d_ws, size_t ws_size,
                              hipStream_t stream) {
  const float* x = (const float*)d_in[0];       // 8192 x 4096
  const float* weight = (const float*)d_in[1];  // 4096 x 4096
  const float* bias = (const float*)d_in[2];    // 4096
  const float* noise = (const float*)d_in[3];   // 8192 x 16
  const float* P = (const float*)d_in[4];       // 4096 x 4096
  float* out = (float*)d_out;                   // 8192 x 4096

  char* ws = (char*)d_ws;
  __bf16* Xb = (__bf16*)ws;                                   // 64 MB
  __bf16* Wb = (__bf16*)(ws + (size_t)NROWS * IN_F * 2);      // 32 MB
  float* Pbt = (float*)(ws + (size_t)NROWS * IN_F * 2 + (size_t)OUT_F * IN_F * 2);  // 256 KB

  pb_kernel<<<IN_F / 4, 256, 0, stream>>>(P, noise, Pbt);
  prep_kernel<<<1024 + 4096, 256, 0, stream>>>(weight, noise, Pbt, Wb, x, Xb);
  gemm_kernel<<<dim3(512), 512, 0, stream>>>(Xb, Wb, bias, out);
}